// Round 5
// baseline (695.970 us; speedup 1.0000x reference)
//
#include <hip/hip_runtime.h>

#define N_NODES 100000
#define N_EDGES 1250000
#define FEATS 64

#define NPB    64                              // nodes per bucket
#define NPB_SH 6
#define NBUCK ((N_NODES + NPB - 1) / NPB)      // 1563
#define CAP    1280                            // mean 800, sd 28 -> +17 sigma (validated R1/R4)
#define TILE   4096
#define NTILES ((N_EDGES + TILE - 1) / TILE)   // 306
#define SROW_PAD 68                            // 16B-aligned rows; bank spread 4d+8li+k

typedef unsigned short ushort8 __attribute__((ext_vector_type(8)));

__device__ __forceinline__ float bf2f(unsigned short u) {
    return __uint_as_float(((unsigned int)u) << 16);
}
__device__ __forceinline__ unsigned short f2bf(float f) {
    unsigned int x = __float_as_uint(f);
    unsigned int lsb = (x >> 16) & 1u;
    x += 0x7fffu + lsb;                 // round-to-nearest-even
    return (unsigned short)(x >> 16);
}

// ---------------------------------------------------------------------------
// ws layout:
//   cursor [2048]            bucket sizes (memset 0; binA atomicAdd, relative)
//   pairs  int[1563*1280]    packed (src<<6 | dst&63), 8.0 MB
//   hb     ushort[6.4M]      bf16 h copy, 12.8 MB        total ~20.8 MB
// ---------------------------------------------------------------------------

// Unchanged from round 4 (passed; ~55 us est): 16 edges/thread, LDS hist,
// direct scatter. TILE=4096 (R2 showed small tiles drown in NBUCK overhead).
__global__ __launch_bounds__(256) void binA_pack_kernel(
        const float* __restrict__ h,
        unsigned short* __restrict__ hb,
        const int* __restrict__ src,
        const int* __restrict__ dst,
        int* __restrict__ cursor,
        int* __restrict__ pairs) {
    // ---- pack prologue (independent of binning) ----
    const int PTOT = N_NODES * FEATS;           // 6.4M, %8 == 0
    for (int i = (blockIdx.x * 256 + threadIdx.x) * 8; i < PTOT;
         i += gridDim.x * 256 * 8) {
        float4 a = *(const float4*)(h + i);
        float4 c = *(const float4*)(h + i + 4);
        ushort8 u;
        u[0] = f2bf(a.x); u[1] = f2bf(a.y); u[2] = f2bf(a.z); u[3] = f2bf(a.w);
        u[4] = f2bf(c.x); u[5] = f2bf(c.y); u[6] = f2bf(c.z); u[7] = f2bf(c.w);
        *(ushort8*)(hb + i) = u;
    }

    // ---- binning ----
    __shared__ int hist[NBUCK];
    __shared__ int base[NBUCK];
    const int t  = threadIdx.x;
    const int e0 = blockIdx.x * TILE + t * 16;
    const bool full = (blockIdx.x + 1) * TILE <= N_EDGES;

    for (int i = t; i < NBUCK; i += 256) hist[i] = 0;
    __syncthreads();

    int d[16], lr[16];
    if (full) {
#pragma unroll
        for (int q = 0; q < 4; ++q) {
            int4 v = *(const int4*)(dst + e0 + q * 4);
            d[q * 4 + 0] = v.x; d[q * 4 + 1] = v.y;
            d[q * 4 + 2] = v.z; d[q * 4 + 3] = v.w;
        }
#pragma unroll
        for (int j = 0; j < 16; ++j) lr[j] = atomicAdd(&hist[d[j] >> NPB_SH], 1);
    } else {
#pragma unroll
        for (int j = 0; j < 16; ++j) {
            if (e0 + j < N_EDGES) {
                d[j]  = dst[e0 + j];
                lr[j] = atomicAdd(&hist[d[j] >> NPB_SH], 1);
            }
        }
    }
    __syncthreads();

    for (int i = t; i < NBUCK; i += 256)
        base[i] = hist[i] ? atomicAdd(&cursor[i], hist[i]) : 0;   // relative
    __syncthreads();

    if (full) {
        int s[16];
#pragma unroll
        for (int q = 0; q < 4; ++q) {
            int4 v = *(const int4*)(src + e0 + q * 4);
            s[q * 4 + 0] = v.x; s[q * 4 + 1] = v.y;
            s[q * 4 + 2] = v.z; s[q * 4 + 3] = v.w;
        }
#pragma unroll
        for (int j = 0; j < 16; ++j) {
            int bk  = d[j] >> NPB_SH;
            int rel = base[bk] + lr[j];
            if (rel < CAP)                       // overflow guard (never hits)
                pairs[(size_t)bk * CAP + rel] = (s[j] << NPB_SH) | (d[j] & (NPB - 1));
        }
    } else {
#pragma unroll
        for (int j = 0; j < 16; ++j) {
            if (e0 + j < N_EDGES) {
                int bk  = d[j] >> NPB_SH;
                int rel = base[bk] + lr[j];
                if (rel < CAP)
                    pairs[(size_t)bk * CAP + rel] =
                        (src[e0 + j] << NPB_SH) | (d[j] & (NPB - 1));
            }
        }
    }
}

// ---------------------------------------------------------------------------
// One block per 64-node bucket. Edge-parallel gather with plain LDS
// atomicAdd (ds_add_f32, fire-and-forget): no counting sort, no ragged
// per-node loop. Round-4 failure was implementation, not structure:
//   - __launch_bounds__(256,4): VGPR budget 128 -> no scratch spill
//     (R4's (256,6) gave VGPR=40 + 376 MB scratch writes = 640 us)
//   - plain atomicAdd on the __shared__ array (canonical lowering)
//   - W loaded to VGPRs only AFTER the edge loop (light loop regalloc)
// ---------------------------------------------------------------------------
__global__ __launch_bounds__(256, 4) void agg_kernel(
        const unsigned short* __restrict__ hb,
        const int* __restrict__ pairs,
        const int* __restrict__ cursor,
        const float* __restrict__ W,    // [o][k] row-major
        const float* __restrict__ bias,
        float* __restrict__ out) {
    __shared__ float srow[NPB][SROW_PAD];   // 17.4 KB
    __shared__ int   spairs[CAP];           // 5 KB

    const int tid  = threadIdx.x;
    const int lane = tid & 63;
    const int wv   = tid >> 6;
    const int gid  = tid >> 3;           // group 0..31 (block-wide)
    const int li   = tid & 7;
    const int fo   = li * 8;             // my 8 feats

    const int b = blockIdx.x;
    int size = cursor[b];
    if (size > CAP) size = CAP;
    const int* bp = pairs + (size_t)b * CAP;

    // zero accumulators + stage this bucket's pairs to LDS (coalesced)
    for (int i = tid; i < NPB * SROW_PAD; i += 256) ((float*)srow)[i] = 0.f;
    for (int i = tid; i < size; i += 256) spairs[i] = bp[i];
    __syncthreads();

    // -- edge-parallel accumulate, 2 edges per group per iteration (MLP) --
    for (int i = gid; i < size; i += 64) {
        const int p0 = spairs[i];                 // LDS broadcast in group
        const int d0 = p0 & (NPB - 1);
        const int i1 = i + 32;
        ushort8 u0 = *(const ushort8*)(hb + (size_t)(p0 >> NPB_SH) * FEATS + fo);
        int d1 = 0;
        ushort8 u1;
        if (i1 < size) {
            const int p1 = spairs[i1];
            d1 = p1 & (NPB - 1);
            u1 = *(const ushort8*)(hb + (size_t)(p1 >> NPB_SH) * FEATS + fo);
        }
#pragma unroll
        for (int k = 0; k < 8; ++k)
            atomicAdd(&srow[d0][fo + k], bf2f(u0[k]));
        if (i1 < size) {
#pragma unroll
            for (int k = 0; k < 8; ++k)
                atomicAdd(&srow[d1][fo + k], bf2f(u1[k]));
        }
    }
    __syncthreads();

    // -- linear + bias + relu (W in VGPRs, loaded after the edge loop) --
    float wr[FEATS];
#pragma unroll
    for (int kk = 0; kk < 16; ++kk) {
        float4 w4 = *(const float4*)(W + (size_t)lane * FEATS + kk * 4);
        wr[kk * 4 + 0] = w4.x;
        wr[kk * 4 + 1] = w4.y;
        wr[kk * 4 + 2] = w4.z;
        wr[kk * 4 + 3] = w4.w;
    }
    const float bv = bias[lane];

    const int n0 = b * NPB + wv * 16;    // 4 waves x 16 nodes
#pragma unroll 4
    for (int q = 0; q < 16; ++q) {
        const int nn = n0 + q;
        if (nn >= N_NODES) break;
        const float4* ar = (const float4*)&srow[wv * 16 + q][0];  // broadcast
        float o_acc = bv;
#pragma unroll
        for (int k4 = 0; k4 < 16; ++k4) {
            float4 r = ar[k4];               // b128 broadcast, conflict-free
            o_acc = fmaf(r.x, wr[k4 * 4 + 0], o_acc);
            o_acc = fmaf(r.y, wr[k4 * 4 + 1], o_acc);
            o_acc = fmaf(r.z, wr[k4 * 4 + 2], o_acc);
            o_acc = fmaf(r.w, wr[k4 * 4 + 3], o_acc);
        }
        out[(size_t)nn * FEATS + lane] = fmaxf(o_acc, 0.0f);
    }
}

extern "C" void kernel_launch(void* const* d_in, const int* in_sizes, int n_in,
                              void* d_out, int out_size, void* d_ws, size_t ws_size,
                              hipStream_t stream) {
    const float* h   = (const float*)d_in[0];
    const int*   src = (const int*)d_in[1];
    const int*   dst = (const int*)d_in[2];
    const float* W   = (const float*)d_in[3];
    const float* b   = (const float*)d_in[4];
    float* out = (float*)d_out;

    int* cursor = (int*)d_ws;                          // 2048 ints
    int* pairs  = cursor + 2048;                       // 1563*1280 ints, 8.0 MB
    unsigned short* hb = (unsigned short*)(pairs + (size_t)NBUCK * CAP);  // 12.8 MB

    hipMemsetAsync(cursor, 0, 2048 * sizeof(int), stream);
    binA_pack_kernel<<<NTILES, 256, 0, stream>>>(h, hb, src, dst, cursor, pairs);
    agg_kernel<<<NBUCK, 256, 0, stream>>>(hb, pairs, cursor, W, b, out);
}

// Round 6
// 600.603 us; speedup vs baseline: 1.1588x; 1.1588x over previous
//
#include <hip/hip_runtime.h>

#define N_NODES 100000
#define N_EDGES 1250000
#define FEATS 64

#define NPB    64                              // nodes per bucket
#define NPB_SH 6
#define NBUCK ((N_NODES + NPB - 1) / NPB)      // 1563
#define CAP    1280                            // mean 800, sd 28 -> +17 sigma (validated R1/R4/R5)
#define TILE   4096
#define NTILES ((N_EDGES + TILE - 1) / TILE)   // 306
#define SROW_PAD 68                            // 272 B rows: 16B-aligned, 2-way avg banking

typedef unsigned short ushort8 __attribute__((ext_vector_type(8)));

__device__ __forceinline__ float bf2f(unsigned short u) {
    return __uint_as_float(((unsigned int)u) << 16);
}
__device__ __forceinline__ unsigned short f2bf(float f) {
    unsigned int x = __float_as_uint(f);
    unsigned int lsb = (x >> 16) & 1u;
    x += 0x7fffu + lsb;                 // round-to-nearest-even
    return (unsigned short)(x >> 16);
}

// ---------------------------------------------------------------------------
// ws layout:
//   cursor [2048]            bucket sizes (memset 0; binA atomicAdd, relative)
//   pairs  int[1563*1280]    packed (src<<6 | dst&63), 8.0 MB
//   hb     ushort[6.4M]      bf16 h copy, 12.8 MB        total ~20.8 MB
// ---------------------------------------------------------------------------

// Unchanged from R4/R5 (passed twice): 16 edges/thread, LDS hist, scatter.
__global__ __launch_bounds__(256) void binA_pack_kernel(
        const float* __restrict__ h,
        unsigned short* __restrict__ hb,
        const int* __restrict__ src,
        const int* __restrict__ dst,
        int* __restrict__ cursor,
        int* __restrict__ pairs) {
    // ---- pack prologue (independent of binning) ----
    const int PTOT = N_NODES * FEATS;           // 6.4M, %8 == 0
    for (int i = (blockIdx.x * 256 + threadIdx.x) * 8; i < PTOT;
         i += gridDim.x * 256 * 8) {
        float4 a = *(const float4*)(h + i);
        float4 c = *(const float4*)(h + i + 4);
        ushort8 u;
        u[0] = f2bf(a.x); u[1] = f2bf(a.y); u[2] = f2bf(a.z); u[3] = f2bf(a.w);
        u[4] = f2bf(c.x); u[5] = f2bf(c.y); u[6] = f2bf(c.z); u[7] = f2bf(c.w);
        *(ushort8*)(hb + i) = u;
    }

    // ---- binning ----
    __shared__ int hist[NBUCK];
    __shared__ int base[NBUCK];
    const int t  = threadIdx.x;
    const int e0 = blockIdx.x * TILE + t * 16;
    const bool full = (blockIdx.x + 1) * TILE <= N_EDGES;

    for (int i = t; i < NBUCK; i += 256) hist[i] = 0;
    __syncthreads();

    int d[16], lr[16];
    if (full) {
#pragma unroll
        for (int q = 0; q < 4; ++q) {
            int4 v = *(const int4*)(dst + e0 + q * 4);
            d[q * 4 + 0] = v.x; d[q * 4 + 1] = v.y;
            d[q * 4 + 2] = v.z; d[q * 4 + 3] = v.w;
        }
#pragma unroll
        for (int j = 0; j < 16; ++j) lr[j] = atomicAdd(&hist[d[j] >> NPB_SH], 1);
    } else {
#pragma unroll
        for (int j = 0; j < 16; ++j) {
            if (e0 + j < N_EDGES) {
                d[j]  = dst[e0 + j];
                lr[j] = atomicAdd(&hist[d[j] >> NPB_SH], 1);
            }
        }
    }
    __syncthreads();

    for (int i = t; i < NBUCK; i += 256)
        base[i] = hist[i] ? atomicAdd(&cursor[i], hist[i]) : 0;   // relative
    __syncthreads();

    if (full) {
        int s[16];
#pragma unroll
        for (int q = 0; q < 4; ++q) {
            int4 v = *(const int4*)(src + e0 + q * 4);
            s[q * 4 + 0] = v.x; s[q * 4 + 1] = v.y;
            s[q * 4 + 2] = v.z; s[q * 4 + 3] = v.w;
        }
#pragma unroll
        for (int j = 0; j < 16; ++j) {
            int bk  = d[j] >> NPB_SH;
            int rel = base[bk] + lr[j];
            if (rel < CAP)                       // overflow guard (never hits)
                pairs[(size_t)bk * CAP + rel] = (s[j] << NPB_SH) | (d[j] & (NPB - 1));
        }
    } else {
#pragma unroll
        for (int j = 0; j < 16; ++j) {
            if (e0 + j < N_EDGES) {
                int bk  = d[j] >> NPB_SH;
                int rel = base[bk] + lr[j];
                if (rel < CAP)
                    pairs[(size_t)bk * CAP + rel] =
                        (src[e0 + j] << NPB_SH) | (d[j] & (NPB - 1));
            }
        }
    }
}

// ---------------------------------------------------------------------------
// One block per 64-node bucket. Edge-parallel gather with LDS atomicAdd
// (ds_add_f32): no counting sort, no ragged per-node loop.
// R4/R5 lesson: the epilogue's wr[64] array spilled to scratch under
// __launch_bounds__ occupancy hints (FETCH 649 MB / WRITE 264 MB scratch
// signature, 600+ us). Fix at source level:
//   - NO per-thread W array: each W float4 is loaded from global right
//     before its FMA (R0's proven remat codegen; W is 16 KB, L2-hot,
//     1 KB/wave coalesced)
//   - plain __launch_bounds__(256), no min-waves hint
// ---------------------------------------------------------------------------
__global__ __launch_bounds__(256) void agg_kernel(
        const unsigned short* __restrict__ hb,
        const int* __restrict__ pairs,
        const int* __restrict__ cursor,
        const float* __restrict__ W,    // [o][k] row-major
        const float* __restrict__ bias,
        float* __restrict__ out) {
    __shared__ float srow[NPB][SROW_PAD];   // 17.4 KB
    __shared__ int   spairs[CAP];           // 5 KB

    const int tid  = threadIdx.x;
    const int lane = tid & 63;
    const int wv   = tid >> 6;
    const int gid  = tid >> 3;           // group 0..31 (block-wide)
    const int li   = tid & 7;
    const int fo   = li * 8;             // my 8 feats

    const int b = blockIdx.x;
    int size = cursor[b];
    if (size > CAP) size = CAP;
    const int* bp = pairs + (size_t)b * CAP;

    // zero accumulators + stage this bucket's pairs to LDS (coalesced)
    for (int i = tid; i < NPB * SROW_PAD; i += 256) ((float*)srow)[i] = 0.f;
    for (int i = tid; i < size; i += 256) spairs[i] = bp[i];
    __syncthreads();

    // -- edge-parallel accumulate, 2 edges per group per iteration (MLP) --
    for (int i = gid; i < size; i += 64) {
        const int p0 = spairs[i];                 // LDS broadcast in group
        const int d0 = p0 & (NPB - 1);
        const int i1 = i + 32;
        ushort8 u0 = *(const ushort8*)(hb + (size_t)(p0 >> NPB_SH) * FEATS + fo);
        int d1 = 0;
        ushort8 u1;
        if (i1 < size) {
            const int p1 = spairs[i1];
            d1 = p1 & (NPB - 1);
            u1 = *(const ushort8*)(hb + (size_t)(p1 >> NPB_SH) * FEATS + fo);
        }
#pragma unroll
        for (int k = 0; k < 8; ++k)
            atomicAdd(&srow[d0][fo + k], bf2f(u0[k]));
        if (i1 < size) {
#pragma unroll
            for (int k = 0; k < 8; ++k)
                atomicAdd(&srow[d1][fo + k], bf2f(u1[k]));
        }
    }
    __syncthreads();

    // -- linear + bias + relu: W float4s loaded per-use from global (L2-hot,
    //    no live W array -> no spill); srow rows read as b128 broadcasts --
    const float bv = bias[lane];
    const float* wrow = W + (size_t)lane * FEATS;

    const int n0 = b * NPB + wv * 16;    // 4 waves x 16 nodes
#pragma unroll 4
    for (int q = 0; q < 16; ++q) {
        const int nn = n0 + q;
        if (nn >= N_NODES) break;
        const float4* ar = (const float4*)&srow[wv * 16 + q][0];  // broadcast
        float o_acc = bv;
#pragma unroll
        for (int k4 = 0; k4 < 16; ++k4) {
            float4 w4 = *(const float4*)(wrow + k4 * 4);  // L2-hot, coalesced
            float4 r  = ar[k4];               // b128 broadcast, conflict-free
            o_acc = fmaf(r.x, w4.x, o_acc);
            o_acc = fmaf(r.y, w4.y, o_acc);
            o_acc = fmaf(r.z, w4.z, o_acc);
            o_acc = fmaf(r.w, w4.w, o_acc);
        }
        out[(size_t)nn * FEATS + lane] = fmaxf(o_acc, 0.0f);
    }
}

extern "C" void kernel_launch(void* const* d_in, const int* in_sizes, int n_in,
                              void* d_out, int out_size, void* d_ws, size_t ws_size,
                              hipStream_t stream) {
    const float* h   = (const float*)d_in[0];
    const int*   src = (const int*)d_in[1];
    const int*   dst = (const int*)d_in[2];
    const float* W   = (const float*)d_in[3];
    const float* b   = (const float*)d_in[4];
    float* out = (float*)d_out;

    int* cursor = (int*)d_ws;                          // 2048 ints
    int* pairs  = cursor + 2048;                       // 1563*1280 ints, 8.0 MB
    unsigned short* hb = (unsigned short*)(pairs + (size_t)NBUCK * CAP);  // 12.8 MB

    hipMemsetAsync(cursor, 0, 2048 * sizeof(int), stream);
    binA_pack_kernel<<<NTILES, 256, 0, stream>>>(h, hb, src, dst, cursor, pairs);
    agg_kernel<<<NBUCK, 256, 0, stream>>>(hb, pairs, cursor, W, b, out);
}

// Round 7
// 167.317 us; speedup vs baseline: 4.1596x; 3.5896x over previous
//
#include <hip/hip_runtime.h>

#define N_NODES 100000
#define N_EDGES 1250000
#define FEATS 64

#define NPB   128                              // nodes per bucket (R0 proven)
#define NBUCK ((N_NODES + NPB - 1) / NPB)      // 782
#define CAP   2304                             // slots/bucket; mean 1600, sd 40 -> +17 sigma
#define TILE  4096
#define NTILES ((N_EDGES + TILE - 1) / TILE)   // 306

typedef unsigned short ushort8 __attribute__((ext_vector_type(8)));

__device__ __forceinline__ float bf2f(unsigned short u) {
    return __uint_as_float(((unsigned int)u) << 16);
}
__device__ __forceinline__ unsigned short f2bf(float f) {
    unsigned int x = __float_as_uint(f);
    unsigned int lsb = (x >> 16) & 1u;
    x += 0x7fffu + lsb;                 // round-to-nearest-even
    return (unsigned short)(x >> 16);
}

// ---------------------------------------------------------------------------
// ws layout (R0 proven):
//   cursor [1024]            bucket sizes (memset 0; binA atomicAdd, relative)
//   pairs  int[782*2304]     packed (src<<7 | dst&127), 7.2 MB
//   hb     ushort[6.4M]      bf16 h copy, 12.8 MB
// ---------------------------------------------------------------------------

// Byte-identical to R0 (proven at 159.6 total).
__global__ __launch_bounds__(256) void binA_pack_kernel(
        const float* __restrict__ h,
        unsigned short* __restrict__ hb,
        const int* __restrict__ src,
        const int* __restrict__ dst,
        int* __restrict__ cursor,
        int* __restrict__ pairs) {
    // ---- pack prologue (independent of binning) ----
    const int PTOT = N_NODES * FEATS;           // 6.4M, %8 == 0
    for (int i = (blockIdx.x * 256 + threadIdx.x) * 8; i < PTOT;
         i += gridDim.x * 256 * 8) {
        float4 a = *(const float4*)(h + i);
        float4 c = *(const float4*)(h + i + 4);
        ushort8 u;
        u[0] = f2bf(a.x); u[1] = f2bf(a.y); u[2] = f2bf(a.z); u[3] = f2bf(a.w);
        u[4] = f2bf(c.x); u[5] = f2bf(c.y); u[6] = f2bf(c.z); u[7] = f2bf(c.w);
        *(ushort8*)(hb + i) = u;
    }

    // ---- binning ----
    __shared__ int hist[NBUCK];
    __shared__ int base[NBUCK];
    const int t  = threadIdx.x;
    const int e0 = blockIdx.x * TILE + t * 16;
    const bool full = (blockIdx.x + 1) * TILE <= N_EDGES;

    for (int i = t; i < NBUCK; i += 256) hist[i] = 0;
    __syncthreads();

    int d[16], lr[16];
    if (full) {
#pragma unroll
        for (int q = 0; q < 4; ++q) {
            int4 v = *(const int4*)(dst + e0 + q * 4);
            d[q * 4 + 0] = v.x; d[q * 4 + 1] = v.y;
            d[q * 4 + 2] = v.z; d[q * 4 + 3] = v.w;
        }
#pragma unroll
        for (int j = 0; j < 16; ++j) lr[j] = atomicAdd(&hist[d[j] >> 7], 1);
    } else {
#pragma unroll
        for (int j = 0; j < 16; ++j) {
            if (e0 + j < N_EDGES) {
                d[j]  = dst[e0 + j];
                lr[j] = atomicAdd(&hist[d[j] >> 7], 1);
            }
        }
    }
    __syncthreads();

    for (int i = t; i < NBUCK; i += 256)
        base[i] = hist[i] ? atomicAdd(&cursor[i], hist[i]) : 0;   // relative
    __syncthreads();

    if (full) {
        int s[16];
#pragma unroll
        for (int q = 0; q < 4; ++q) {
            int4 v = *(const int4*)(src + e0 + q * 4);
            s[q * 4 + 0] = v.x; s[q * 4 + 1] = v.y;
            s[q * 4 + 2] = v.z; s[q * 4 + 3] = v.w;
        }
#pragma unroll
        for (int j = 0; j < 16; ++j) {
            int bk  = d[j] >> 7;
            int rel = base[bk] + lr[j];
            if (rel < CAP)                       // overflow guard (never hits)
                pairs[(size_t)bk * CAP + rel] = (s[j] << 7) | (d[j] & (NPB - 1));
        }
    } else {
#pragma unroll
        for (int j = 0; j < 16; ++j) {
            if (e0 + j < N_EDGES) {
                int bk  = d[j] >> 7;
                int rel = base[bk] + lr[j];
                if (rel < CAP)
                    pairs[(size_t)bk * CAP + rel] =
                        (src[e0 + j] << 7) | (d[j] & (NPB - 1));
            }
        }
    }
}

// ---------------------------------------------------------------------------
// R0's proven agg structure (counting sort + 8-lane-group register-accumulate
// gather) with ONE change: 512 threads/block (8 waves) instead of 256.
//   - R0 was latency-bound: 26% occupancy, 88 MB HBM at only 1.4 TB/s.
//   - 8 waves/block -> ~2x resident waves & outstanding gathers; sort cost
//     amortized over 2x threads; 2 passes of 64 nodes instead of 4 of 32.
//   - LDS 27 KB (5 blk/CU); wave limit 4 blk/CU = 100% theoretical occ.
//   - Inner gather/epilogue code byte-identical to R0 (proven codegen:
//     VGPR=60, zero scratch). LDS-atomic variants (R4-R6) are dead: DS-unit
//     RMW throughput wall (10M lane-atomics -> 500 us at 4% VALUBusy).
// ---------------------------------------------------------------------------
__global__ __launch_bounds__(512) void agg_kernel(
        const unsigned short* __restrict__ hb,
        const int* __restrict__ pairs,
        const int* __restrict__ cursor,
        const float* __restrict__ W,    // [o][k] row-major
        const float* __restrict__ bias,
        float* __restrict__ out) {
    __shared__ int   ssrc[CAP];          // 9.2 KB sorted src ids
    __shared__ int   lcnt[NPB];
    __shared__ int   loff[NPB + 1];
    __shared__ int   lcur[NPB];
    __shared__ float srow[8][8][FEATS];  // 16 KB (8 waves x 8 groups)

    const int tid  = threadIdx.x;
    const int lane = tid & 63;
    const int wv   = tid >> 6;           // wave 0..7
    const int g    = lane >> 3;          // group 0..7
    const int li   = lane & 7;
    const int fo   = li * 8;             // my 8 feats

    float wr[FEATS];
#pragma unroll
    for (int kk = 0; kk < 16; ++kk) {
        float4 w4 = *(const float4*)(W + (size_t)lane * FEATS + kk * 4);
        wr[kk * 4 + 0] = w4.x;
        wr[kk * 4 + 1] = w4.y;
        wr[kk * 4 + 2] = w4.z;
        wr[kk * 4 + 3] = w4.w;
    }
    const float bv = bias[lane];

    const int b = blockIdx.x;
    int size = cursor[b];
    if (size > CAP) size = CAP;
    const int* bp = pairs + (size_t)b * CAP;

    // -- counting sort by dst&127 --
    if (tid < NPB) lcnt[tid] = 0;
    __syncthreads();
    for (int i = tid; i < size; i += 512) atomicAdd(&lcnt[bp[i] & (NPB - 1)], 1);
    __syncthreads();
    if (tid < NPB) lcur[tid] = lcnt[tid];      // scan scratch
    __syncthreads();
    for (int off = 1; off < NPB; off <<= 1) {
        int y = 0;
        if (tid < NPB && tid >= off) y = lcur[tid - off];
        __syncthreads();
        if (tid < NPB) lcur[tid] += y;
        __syncthreads();
    }
    if (tid < NPB) loff[tid + 1] = lcur[tid];  // inclusive -> loff[1..128]
    if (tid == 0) loff[0] = 0;
    __syncthreads();
    if (tid < NPB) lcur[tid] = loff[tid];
    __syncthreads();
    for (int i = tid; i < size; i += 512) {
        int p = bp[i];
        int r = atomicAdd(&lcur[p & (NPB - 1)], 1);
        ssrc[r] = p >> 7;
    }
    __syncthreads();

    // -- gather + linear, 2 passes of 64 nodes (8 waves x 8 groups) --
#pragma unroll
    for (int pass = 0; pass < 2; ++pass) {
        const int ln  = pass * 64 + wv * 8 + g;
        const int beg = loff[ln];
        const int m   = loff[ln + 1] - beg;

        float acc0[8], acc1[8];
#pragma unroll
        for (int i = 0; i < 8; ++i) { acc0[i] = 0.f; acc1[i] = 0.f; }

        for (int base = 0; __any(base < m); base += 8) {
#pragma unroll
            for (int t = 0; t < 8; t += 2) {
                const int i0 = base + t, i1 = base + t + 1;
                int r0 = (i0 < m) ? ssrc[beg + i0] : 0;
                int r1 = (i1 < m) ? ssrc[beg + i1] : 0;
                if (i0 < m) {
                    ushort8 u = *(const ushort8*)(hb + (size_t)r0 * FEATS + fo);
#pragma unroll
                    for (int i = 0; i < 8; ++i) acc0[i] += bf2f(u[i]);
                }
                if (i1 < m) {
                    ushort8 u = *(const ushort8*)(hb + (size_t)r1 * FEATS + fo);
#pragma unroll
                    for (int i = 0; i < 8; ++i) acc1[i] += bf2f(u[i]);
                }
            }
        }
#pragma unroll
        for (int i = 0; i < 8; ++i) acc0[i] += acc1[i];

        *(float4*)&srow[wv][g][fo]     = make_float4(acc0[0], acc0[1], acc0[2], acc0[3]);
        *(float4*)&srow[wv][g][fo + 4] = make_float4(acc0[4], acc0[5], acc0[6], acc0[7]);
        // srow is wave-private: in-wave LDS ordering, no barrier needed

        const int n0 = b * NPB + pass * 64 + wv * 8;
#pragma unroll
        for (int gg = 0; gg < 8; ++gg) {
            const int nn = n0 + gg;
            if (nn >= N_NODES) break;
            const float4* ar = (const float4*)&srow[wv][gg][0];
            float o_acc = bv;
#pragma unroll
            for (int k4 = 0; k4 < 16; ++k4) {
                float4 r = ar[k4];               // b128 broadcast
                o_acc = fmaf(r.x, wr[k4 * 4 + 0], o_acc);
                o_acc = fmaf(r.y, wr[k4 * 4 + 1], o_acc);
                o_acc = fmaf(r.z, wr[k4 * 4 + 2], o_acc);
                o_acc = fmaf(r.w, wr[k4 * 4 + 3], o_acc);
            }
            out[(size_t)nn * FEATS + lane] = fmaxf(o_acc, 0.0f);
        }
    }
}

extern "C" void kernel_launch(void* const* d_in, const int* in_sizes, int n_in,
                              void* d_out, int out_size, void* d_ws, size_t ws_size,
                              hipStream_t stream) {
    const float* h   = (const float*)d_in[0];
    const int*   src = (const int*)d_in[1];
    const int*   dst = (const int*)d_in[2];
    const float* W   = (const float*)d_in[3];
    const float* b   = (const float*)d_in[4];
    float* out = (float*)d_out;

    int* cursor = (int*)d_ws;                          // 1024 ints
    int* pairs  = cursor + 1024;                       // 782*2304 = 1.80M ints
    unsigned short* hb = (unsigned short*)(pairs + (size_t)NBUCK * CAP);  // 6.4M

    hipMemsetAsync(cursor, 0, 1024 * sizeof(int), stream);
    binA_pack_kernel<<<NTILES, 256, 0, stream>>>(h, hb, src, dst, cursor, pairs);
    agg_kernel<<<NBUCK, 512, 0, stream>>>(hb, pairs, cursor, W, b, out);
}